// Round 8
// baseline (58.109 us; speedup 1.0000x reference)
//
#include <hip/hip_runtime.h>
#include <hip/hip_cooperative_groups.h>
#include <hip/hip_bf16.h>
#include <math.h>

namespace cg = cooperative_groups;

#define GRID_RES 128
#define M_TOT (GRID_RES * GRID_RES)
#define N_PTS 4096
#define B_SZ 4
#define KS 16              // K chunks
#define GT 4               // gy slabs
#define SLAB 32            // rows per slab (128/GT)
#define KC 256             // K points per block (N_PTS/KS)
#define KP 264             // padded ushort row stride (528 B)
// exp(-0.5*d^2/sigma^2), sigma=0.1 -> exp2(-72.1347...*d^2)
#define NEG50_LOG2E -72.134752044448170f

typedef __attribute__((ext_vector_type(8))) short short8;
typedef __attribute__((ext_vector_type(4))) float f32x4;

static __device__ __forceinline__ unsigned short f2bf(float f) {
    __hip_bfloat16 h = __float2bfloat16(f);   // RNE
    unsigned short u;
    __builtin_memcpy(&u, &h, 2);
    return u;
}
static __device__ __forceinline__ unsigned int pack_bf16(float a, float b) {
    return (unsigned int)f2bf(a) | ((unsigned int)f2bf(b) << 16);
}
static __device__ __forceinline__ float bf2f(unsigned short u) {
    unsigned int v = ((unsigned int)u) << 16;
    float f;
    __builtin_memcpy(&f, &v, 4);
    return f;
}

// ---- Single cooperative kernel: fused MFMA GEMM -> grid.sync -> reduce ----
// grid (KS, GT, B) = 256 blocks x 512 threads, 1 block/CU (co-resident).
// Phase 1 (per block ks,gt,b): generate bf16 tiles Wy/Yw [32][256], Wx [128][256]
// in LDS, 8 waves MFMA (waves 0-3: ch0, 4-7: ch1), write bf16
// partial[ks][b][ch][gy][gx]. Phase 2 (after grid sync): each of the first
// 65536 threads sums its cell over ks (fixed order -> deterministic) + normalizes.
__global__ __launch_bounds__(512) void fused_all(const float* __restrict__ x_c,
                                                 const float* __restrict__ y_c,
                                                 const int* __restrict__ mask,
                                                 const float* __restrict__ gp,
                                                 unsigned short* __restrict__ partial,
                                                 float* __restrict__ out) {
    const int ks = blockIdx.x;
    const int gt = blockIdx.y;
    const int b  = blockIdx.z;
    const int t  = threadIdx.x;      // 0..511
    const int n0 = ks * KC;
    const int gy0 = gt * SLAB;
    const size_t inoff = (size_t)b * N_PTS;

    __shared__ __align__(16) unsigned short Wy_lds[SLAB][KP];   // 16.9 KB
    __shared__ __align__(16) unsigned short Yw_lds[SLAB][KP];   // 16.9 KB
    __shared__ __align__(16) unsigned short Wx_lds[128][KP];    // 67.6 KB
    __shared__ float pxs[KC], pys[KC], s0s[KC], s1s[KC];
    __shared__ float cxs[128], cys[SLAB];

    // ---- stage inputs ----
    if (t < KC) {
        const float2 xy = *(const float2*)&x_c[(inoff + n0 + t) * 2];
        pxs[t] = xy.x;
        pys[t] = xy.y;
        const float mk = (mask[inoff + n0 + t] != 0) ? 1.0f : 0.0f;
        s0s[t] = mk;
        s1s[t] = mk * y_c[inoff + n0 + t];
    } else if (t < 384) {
        cxs[t - 256] = gp[t - 256];                              // grid_x row 0
    } else if (t < 384 + SLAB) {
        cys[t - 384] = gp[M_TOT + (gy0 + t - 384) * GRID_RES];   // grid_y col 0
    }
    __syncthreads();

    // ---- generate tiles: thread owns k-pair (2*k2, 2*k2+1) ----
    {
        const int k2 = t & 127;
        const int r0 = t >> 7;       // 0..3
        const float px0 = pxs[2 * k2], px1 = pxs[2 * k2 + 1];
        const float py0 = pys[2 * k2], py1 = pys[2 * k2 + 1];
        const float m0  = s0s[2 * k2], m1  = s0s[2 * k2 + 1];
        const float v0  = s1s[2 * k2], v1  = s1s[2 * k2 + 1];
        #pragma unroll 4
        for (int j = 0; j < 32; ++j) {          // Wx: 128 rows
            const int r = r0 + 4 * j;
            const float cb = cxs[r];
            const float d0 = px0 - cb, d1 = px1 - cb;
            *(unsigned int*)&Wx_lds[r][2 * k2] =
                pack_bf16(exp2f(NEG50_LOG2E * d0 * d0), exp2f(NEG50_LOG2E * d1 * d1));
        }
        #pragma unroll 2
        for (int j = 0; j < 8; ++j) {           // Wy/Yw: 32 rows
            const int r = r0 + 4 * j;
            const float ca = cys[r];
            const float d0 = py0 - ca, d1 = py1 - ca;
            const float w0 = exp2f(NEG50_LOG2E * d0 * d0);
            const float w1 = exp2f(NEG50_LOG2E * d1 * d1);
            *(unsigned int*)&Wy_lds[r][2 * k2] = pack_bf16(w0 * m0, w1 * m1);
            *(unsigned int*)&Yw_lds[r][2 * k2] = pack_bf16(w0 * v0, w1 * v1);
        }
    }
    __syncthreads();

    // ---- MFMA: 8 waves; ch = w>>2, cols (w&3)*32 (2 frags), rows 0/16 ----
    {
        const int w  = t >> 6;
        const int l  = t & 63;
        const int lr = l & 15;
        const int lg = l >> 4;
        const int ch = w >> 2;
        const int c0 = (w & 3) * 32;
        const unsigned short (*A)[KP] = ch ? Yw_lds : Wy_lds;

        f32x4 acc[2][2];
        #pragma unroll
        for (int rf = 0; rf < 2; ++rf)
            #pragma unroll
            for (int cf = 0; cf < 2; ++cf)
                acc[rf][cf] = (f32x4){0.f, 0.f, 0.f, 0.f};

        #pragma unroll
        for (int s = 0; s < 8; ++s) {
            const int koff = s * 32 + lg * 8;
            const short8 a0 = *(const short8*)&A[lr][koff];
            const short8 a1 = *(const short8*)&A[16 + lr][koff];
            const short8 b0 = *(const short8*)&Wx_lds[c0 + lr][koff];
            const short8 b1 = *(const short8*)&Wx_lds[c0 + 16 + lr][koff];
            acc[0][0] = __builtin_amdgcn_mfma_f32_16x16x32_bf16(a0, b0, acc[0][0], 0, 0, 0);
            acc[0][1] = __builtin_amdgcn_mfma_f32_16x16x32_bf16(a0, b1, acc[0][1], 0, 0, 0);
            acc[1][0] = __builtin_amdgcn_mfma_f32_16x16x32_bf16(a1, b0, acc[1][0], 0, 0, 0);
            acc[1][1] = __builtin_amdgcn_mfma_f32_16x16x32_bf16(a1, b1, acc[1][1], 0, 0, 0);
        }

        // write bf16 partial: C/D layout col=lane&15, row=(lane>>4)*4+reg
        unsigned short* pt = partial + ((((size_t)ks * B_SZ + b) * 2 + ch) << 14);
        #pragma unroll
        for (int rf = 0; rf < 2; ++rf)
            #pragma unroll
            for (int cf = 0; cf < 2; ++cf)
                #pragma unroll
                for (int r = 0; r < 4; ++r) {
                    const int row = gy0 + rf * 16 + lg * 4 + r;
                    const int col = c0 + cf * 16 + lr;
                    pt[row * GRID_RES + col] = f2bf(acc[rf][cf][r]);
                }
    }

    // ---- grid-wide barrier: all partials visible ----
    cg::this_grid().sync();

    // ---- Phase 2: reduce + normalize. One cell per thread (first 65536). ----
    const int flat = blockIdx.x + KS * (blockIdx.y + GT * blockIdx.z);
    const int gidx = flat * 512 + t;
    if (gidx < B_SZ * M_TOT) {
        const int b2 = gidx >> 14;
        const int m  = gidx & (M_TOT - 1);
        float dsum = 0.f, vsum = 0.f;
        #pragma unroll 4
        for (int k2 = 0; k2 < KS; ++k2) {
            dsum += bf2f(partial[((((size_t)k2 * B_SZ + b2) * 2 + 0) << 14) + m]);
            vsum += bf2f(partial[((((size_t)k2 * B_SZ + b2) * 2 + 1) << 14) + m]);
        }
        out[(((size_t)b2 * 2 + 0) << 14) + m] = dsum;
        out[(((size_t)b2 * 2 + 1) << 14) + m] = vsum / (dsum + 1e-5f);
    }
}

extern "C" void kernel_launch(void* const* d_in, const int* in_sizes, int n_in,
                              void* d_out, int out_size, void* d_ws, size_t ws_size,
                              hipStream_t stream) {
    const float* x_c  = (const float*)d_in[0];   // (B,N,2)
    const float* y_c  = (const float*)d_in[1];   // (B,N,1)
    const float* gp   = (const float*)d_in[2];   // (2,M)
    const int* mask   = (const int*)d_in[3];     // (B,N) bool -> int32
    float* out = (float*)d_out;                  // (B,2,128,128)

    unsigned short* partial = (unsigned short*)d_ws;   // KS*B*2*M bf16 = 4.2 MB

    void* args[] = {(void*)&x_c, (void*)&y_c, (void*)&mask, (void*)&gp,
                    (void*)&partial, (void*)&out};
    hipLaunchCooperativeKernel((const void*)fused_all, dim3(KS, GT, B_SZ), dim3(512),
                               args, 0, stream);
}

// Round 9
// 16.549 us; speedup vs baseline: 3.5114x; 3.5114x over previous
//
#include <hip/hip_runtime.h>
#include <hip/hip_bf16.h>
#include <math.h>

#define GRID_RES 128
#define M_TOT (GRID_RES * GRID_RES)
#define N_PTS 4096
#define B_SZ 4
#define KS 16              // K chunks
#define GT 4               // gy slabs
#define SLAB 32            // rows per slab (128/GT)
#define KC 256             // K points per block (N_PTS/KS)
#define KP 264             // padded ushort row stride (528 B)
// exp(-0.5*d^2/sigma^2), sigma=0.1 -> exp2(-72.1347...*d^2)
#define NEG50_LOG2E -72.134752044448170f

typedef __attribute__((ext_vector_type(8))) short short8;
typedef __attribute__((ext_vector_type(4))) short short4v;
typedef __attribute__((ext_vector_type(4))) float f32x4;

static __device__ __forceinline__ unsigned short f2bf(float f) {
    __hip_bfloat16 h = __float2bfloat16(f);   // RNE
    unsigned short u;
    __builtin_memcpy(&u, &h, 2);
    return u;
}
static __device__ __forceinline__ unsigned int pack_bf16(float a, float b) {
    return (unsigned int)f2bf(a) | ((unsigned int)f2bf(b) << 16);
}
static __device__ __forceinline__ float bf2f(unsigned short u) {
    unsigned int v = ((unsigned int)u) << 16;
    float f;
    __builtin_memcpy(&f, &v, 4);
    return f;
}

// ---- Fused MFMA kernel: merged channels, bf16 K-partials (r7 structure) ----
// grid (KS, GT, B) = 256 blocks x 512 threads. Block (ks, gt, b):
// output slab = rows [gt*32, gt*32+32) x 128 gx x 2 ch over K-chunk ks (256 pts).
// Generates bf16 tiles Wy/Yw [32][256], Wx [128][256] in LDS, 8 waves MFMA
// (waves 0-3: ch0, waves 4-7: ch1), writes bf16 partial[ks][b][ch][gy][gx].
__global__ __launch_bounds__(512) void mfma_gemm(const float* __restrict__ x_c,
                                                 const float* __restrict__ y_c,
                                                 const int* __restrict__ mask,
                                                 const float* __restrict__ gp,
                                                 unsigned short* __restrict__ partial) {
    const int ks = blockIdx.x;
    const int gt = blockIdx.y;
    const int b  = blockIdx.z;
    const int t  = threadIdx.x;      // 0..511
    const int n0 = ks * KC;
    const int gy0 = gt * SLAB;
    const size_t inoff = (size_t)b * N_PTS;

    __shared__ __align__(16) unsigned short Wy_lds[SLAB][KP];   // 16.9 KB
    __shared__ __align__(16) unsigned short Yw_lds[SLAB][KP];   // 16.9 KB
    __shared__ __align__(16) unsigned short Wx_lds[128][KP];    // 67.6 KB
    __shared__ float pxs[KC], pys[KC], s0s[KC], s1s[KC];
    __shared__ float cxs[128], cys[SLAB];

    // ---- stage inputs ----
    if (t < KC) {
        const float2 xy = *(const float2*)&x_c[(inoff + n0 + t) * 2];
        pxs[t] = xy.x;
        pys[t] = xy.y;
        const float mk = (mask[inoff + n0 + t] != 0) ? 1.0f : 0.0f;
        s0s[t] = mk;
        s1s[t] = mk * y_c[inoff + n0 + t];
    } else if (t < 384) {
        cxs[t - 256] = gp[t - 256];                              // grid_x row 0
    } else if (t < 384 + SLAB) {
        cys[t - 384] = gp[M_TOT + (gy0 + t - 384) * GRID_RES];   // grid_y col 0
    }
    __syncthreads();

    // ---- generate tiles: thread owns k-pair (2*k2, 2*k2+1) ----
    {
        const int k2 = t & 127;
        const int r0 = t >> 7;       // 0..3
        const float px0 = pxs[2 * k2], px1 = pxs[2 * k2 + 1];
        const float py0 = pys[2 * k2], py1 = pys[2 * k2 + 1];
        const float m0  = s0s[2 * k2], m1  = s0s[2 * k2 + 1];
        const float v0  = s1s[2 * k2], v1  = s1s[2 * k2 + 1];
        #pragma unroll 4
        for (int j = 0; j < 32; ++j) {          // Wx: 128 rows
            const int r = r0 + 4 * j;
            const float cb = cxs[r];
            const float d0 = px0 - cb, d1 = px1 - cb;
            *(unsigned int*)&Wx_lds[r][2 * k2] =
                pack_bf16(exp2f(NEG50_LOG2E * d0 * d0), exp2f(NEG50_LOG2E * d1 * d1));
        }
        #pragma unroll 2
        for (int j = 0; j < 8; ++j) {           // Wy/Yw: 32 rows
            const int r = r0 + 4 * j;
            const float ca = cys[r];
            const float d0 = py0 - ca, d1 = py1 - ca;
            const float w0 = exp2f(NEG50_LOG2E * d0 * d0);
            const float w1 = exp2f(NEG50_LOG2E * d1 * d1);
            *(unsigned int*)&Wy_lds[r][2 * k2] = pack_bf16(w0 * m0, w1 * m1);
            *(unsigned int*)&Yw_lds[r][2 * k2] = pack_bf16(w0 * v0, w1 * v1);
        }
    }
    __syncthreads();

    // ---- MFMA: 8 waves; ch = w>>2, cols (w&3)*32 (2 frags), rows 0/16 ----
    const int w  = t >> 6;
    const int l  = t & 63;
    const int lr = l & 15;
    const int lg = l >> 4;
    const int ch = w >> 2;
    const int c0 = (w & 3) * 32;
    const unsigned short (*A)[KP] = ch ? Yw_lds : Wy_lds;

    f32x4 acc[2][2];
    #pragma unroll
    for (int rf = 0; rf < 2; ++rf)
        #pragma unroll
        for (int cf = 0; cf < 2; ++cf)
            acc[rf][cf] = (f32x4){0.f, 0.f, 0.f, 0.f};

    #pragma unroll
    for (int s = 0; s < 8; ++s) {
        const int koff = s * 32 + lg * 8;
        const short8 a0 = *(const short8*)&A[lr][koff];
        const short8 a1 = *(const short8*)&A[16 + lr][koff];
        const short8 b0 = *(const short8*)&Wx_lds[c0 + lr][koff];
        const short8 b1 = *(const short8*)&Wx_lds[c0 + 16 + lr][koff];
        acc[0][0] = __builtin_amdgcn_mfma_f32_16x16x32_bf16(a0, b0, acc[0][0], 0, 0, 0);
        acc[0][1] = __builtin_amdgcn_mfma_f32_16x16x32_bf16(a0, b1, acc[0][1], 0, 0, 0);
        acc[1][0] = __builtin_amdgcn_mfma_f32_16x16x32_bf16(a1, b0, acc[1][0], 0, 0, 0);
        acc[1][1] = __builtin_amdgcn_mfma_f32_16x16x32_bf16(a1, b1, acc[1][1], 0, 0, 0);
    }

    // ---- write bf16 partial: C/D layout col=lane&15, row=(lane>>4)*4+reg ----
    unsigned short* pt = partial + ((((size_t)ks * B_SZ + b) * 2 + ch) << 14);
    #pragma unroll
    for (int rf = 0; rf < 2; ++rf)
        #pragma unroll
        for (int cf = 0; cf < 2; ++cf)
            #pragma unroll
            for (int r = 0; r < 4; ++r) {
                const int row = gy0 + rf * 16 + lg * 4 + r;
                const int col = c0 + cf * 16 + lr;
                pt[row * GRID_RES + col] = f2bf(acc[rf][cf][r]);
            }
}

// ------------- reduce bf16 K-partials + normalize (64 blocks) ----------------
__global__ __launch_bounds__(256) void reduce_kernel(const unsigned short* __restrict__ partial,
                                                     float* __restrict__ out) {
    const int idx = blockIdx.x * 256 + threadIdx.x;   // 0 .. B*M/4-1
    const int b  = idx >> 12;
    const int m0 = (idx & 4095) * 4;
    float d[4], v[4];
    #pragma unroll
    for (int j = 0; j < 4; ++j) { d[j] = 0.f; v[j] = 0.f; }
    #pragma unroll
    for (int ks = 0; ks < KS; ++ks) {
        const short4v pd = *(const short4v*)&partial[((((size_t)ks * B_SZ + b) * 2 + 0) << 14) + m0];
        const short4v pv = *(const short4v*)&partial[((((size_t)ks * B_SZ + b) * 2 + 1) << 14) + m0];
        #pragma unroll
        for (int j = 0; j < 4; ++j) {
            d[j] += bf2f((unsigned short)pd[j]);
            v[j] += bf2f((unsigned short)pv[j]);
        }
    }
    float* od = out + (((size_t)b * 2 + 0) << 14) + m0;
    float* ov = out + (((size_t)b * 2 + 1) << 14) + m0;
    *(float4*)od = make_float4(d[0], d[1], d[2], d[3]);
    *(float4*)ov = make_float4(v[0] / (d[0] + 1e-5f), v[1] / (d[1] + 1e-5f),
                               v[2] / (d[2] + 1e-5f), v[3] / (d[3] + 1e-5f));
}

extern "C" void kernel_launch(void* const* d_in, const int* in_sizes, int n_in,
                              void* d_out, int out_size, void* d_ws, size_t ws_size,
                              hipStream_t stream) {
    const float* x_c  = (const float*)d_in[0];   // (B,N,2)
    const float* y_c  = (const float*)d_in[1];   // (B,N,1)
    const float* gp   = (const float*)d_in[2];   // (2,M)
    const int* mask   = (const int*)d_in[3];     // (B,N) bool -> int32
    float* out = (float*)d_out;                  // (B,2,128,128)

    unsigned short* partial = (unsigned short*)d_ws;   // KS*B*2*M bf16 = 4.2 MB

    mfma_gemm<<<dim3(KS, GT, B_SZ), 512, 0, stream>>>(x_c, y_c, mask, gp, partial);
    reduce_kernel<<<(B_SZ * M_TOT / 4) / 256, 256, 0, stream>>>(partial, out);
}